// Round 1
// baseline (192.998 us; speedup 1.0000x reference)
//
#include <hip/hip_runtime.h>
#include <hip/hip_bf16.h>

#define D_IN 1386
#define EPS 1e-5f

typedef __attribute__((ext_vector_type(8))) short short8v;
typedef __attribute__((ext_vector_type(4))) float f32x4;

__device__ inline unsigned short bf16rne(float f) {
    unsigned int u = __float_as_uint(f);
    u += 0x7FFFu + ((u >> 16) & 1u);
    return (unsigned short)(u >> 16);
}
__device__ inline float bfbits_to_f(unsigned short b) {
    return __uint_as_float(((unsigned int)b) << 16);
}

union S8U { short8v s; unsigned int u[4]; };

// ---------------- Kernel 1: y = x_flat @ fc1_w.T  (no bias/bn yet) ----------
// block: 256 threads, 32 samples. thread: h = t&63, group g = t>>6 -> 8 samples.
__global__ __launch_bounds__(256) void fc1_kernel(const float* __restrict__ x,
                                                  const float* __restrict__ w,
                                                  float* __restrict__ y)
{
    __shared__ float xs[32 * 64];
    __shared__ float ws[64 * 66];   // +2 pad: b64 reads land on (2h+k)%32 banks
    const int t  = threadIdx.x;
    const int h  = t & 63;
    const int g  = t >> 6;
    const int nb = blockIdx.x * 32;

    float acc[8];
#pragma unroll
    for (int j = 0; j < 8; ++j) acc[j] = 0.f;

    for (int kc = 0; kc < 22; ++kc) {
        const int k0 = kc * 64;
        // stage x[32][64] (float2 loads, coalesced)
#pragma unroll
        for (int i = 0; i < 4; ++i) {
            int idx = t + 256 * i;            // 0..1023
            int row = idx >> 5;               // 0..31
            int c2  = (idx & 31) * 2;         // 0..62 (even)
            int k   = k0 + c2;
            float2 v = make_float2(0.f, 0.f);
            if (k + 1 < D_IN) v = *(const float2*)&x[(size_t)(nb + row) * D_IN + k];
            *(float2*)&xs[row * 64 + c2] = v;
        }
        // stage w[64][64-chunk] into ws[h][k_local] (rows from L2, 355 KB hot)
#pragma unroll
        for (int i = 0; i < 8; ++i) {
            int idx = t + 256 * i;            // 0..2047
            int hw  = idx & 63;
            int c2  = (idx >> 6) * 2;         // 0..62
            int k   = k0 + c2;
            float2 v = make_float2(0.f, 0.f);
            if (k + 1 < D_IN) v = *(const float2*)&w[(size_t)hw * D_IN + k];
            *(float2*)&ws[hw * 66 + c2] = v;
        }
        __syncthreads();
#pragma unroll
        for (int k4 = 0; k4 < 16; ++k4) {
            float2 w0 = *(const float2*)&ws[h * 66 + k4 * 4];
            float2 w1 = *(const float2*)&ws[h * 66 + k4 * 4 + 2];
#pragma unroll
            for (int j = 0; j < 8; ++j) {
                float4 xv = *(const float4*)&xs[(g * 8 + j) * 64 + k4 * 4];
                acc[j] = fmaf(xv.x, w0.x, acc[j]);
                acc[j] = fmaf(xv.y, w0.y, acc[j]);
                acc[j] = fmaf(xv.z, w1.x, acc[j]);
                acc[j] = fmaf(xv.w, w1.y, acc[j]);
            }
        }
        __syncthreads();
    }
#pragma unroll
    for (int j = 0; j < 8; ++j)
        y[(size_t)(nb + g * 8 + j) * 64 + h] = acc[j];
}

// ---------------- Kernel 2: 64-step LIF recurrence via MFMA -----------------
// One wave = 16 samples. z[h'][n] = W2' (A, rows h') x s1^T (B, cols n).
// B/LIF1 state layout: lane l: n = n0+(l&15), h_in = 32*Hh + 8*(l>>4) + e.
// D/LIF2 state layout (verified m89): n = l&15, h' = 16*T + 4*(l>>4) + q.
__global__ __launch_bounds__(256) void snn_kernel(
    const float* __restrict__ y,
    const float* __restrict__ fc1_b,
    const float* __restrict__ bn1_g, const float* __restrict__ bn1_b,
    const float* __restrict__ bn1_m, const float* __restrict__ bn1_v,
    const float* __restrict__ fc2_w, const float* __restrict__ fc2_b,
    const float* __restrict__ bn2_g, const float* __restrict__ bn2_b,
    const float* __restrict__ bn2_m, const float* __restrict__ bn2_v,
    const float* __restrict__ cls_w, const float* __restrict__ cls_b,
    float* __restrict__ out)
{
    const int lane = threadIdx.x & 63;
    const int wid  = threadIdx.x >> 6;
    const int n0   = blockIdx.x * 64 + wid * 16;
    const int r    = lane & 15;
    const int grp  = lane >> 4;

    // --- A fragments: W2'[h'][k] with bn2 scale folded, hi/lo bf16 split ---
    short8v Whi[4][2], Wlo[4][2];
#pragma unroll
    for (int T = 0; T < 4; ++T) {
        const int hp = 16 * T + r;
        const float scale = bn2_g[hp] / sqrtf(bn2_v[hp] + EPS);
#pragma unroll
        for (int Hh = 0; Hh < 2; ++Hh) {
            S8U hi, lo;
#pragma unroll
            for (int d = 0; d < 4; ++d) {
                const int kk = 32 * Hh + 8 * grp + 2 * d;
                float w0 = fc2_w[hp * 64 + kk]     * scale;
                float w1 = fc2_w[hp * 64 + kk + 1] * scale;
                unsigned short h0 = bf16rne(w0), h1 = bf16rne(w1);
                unsigned short l0 = bf16rne(w0 - bfbits_to_f(h0));
                unsigned short l1 = bf16rne(w1 - bfbits_to_f(h1));
                hi.u[d] = (unsigned int)h0 | ((unsigned int)h1 << 16);
                lo.u[d] = (unsigned int)l0 | ((unsigned int)l1 << 16);
            }
            Whi[T][Hh] = hi.s;
            Wlo[T][Hh] = lo.s;
        }
    }

    // --- a1 in B layout ---
    float a1[16];
#pragma unroll
    for (int Hh = 0; Hh < 2; ++Hh)
#pragma unroll
        for (int e = 0; e < 8; ++e) {
            const int hin = 32 * Hh + 8 * grp + e;
            float yv = y[(size_t)(n0 + r) * 64 + hin] + fc1_b[hin];
            float s1v = bn1_g[hin] / sqrtf(bn1_v[hin] + EPS);
            a1[Hh * 8 + e] = (yv - bn1_m[hin]) * s1v + bn1_b[hin];
        }

    // --- bias2' in D layout ---
    float biasD[16];
#pragma unroll
    for (int T = 0; T < 4; ++T)
#pragma unroll
        for (int q = 0; q < 4; ++q) {
            const int hp = 16 * T + 4 * grp + q;
            const float scale = bn2_g[hp] / sqrtf(bn2_v[hp] + EPS);
            biasD[4 * T + q] = (fc2_b[hp] - bn2_m[hp]) * scale + bn2_b[hp];
        }

    float v1[16], v2[16], cnt[16];
#pragma unroll
    for (int i = 0; i < 16; ++i) { v1[i] = 0.f; v2[i] = 0.f; cnt[i] = 0.f; }

#pragma unroll 2
    for (int t = 0; t < 64; ++t) {
        // LIF1 + pack spikes as bf16 {0,1} into B fragments
        S8U s0, s1f;
#pragma unroll
        for (int Hh = 0; Hh < 2; ++Hh)
#pragma unroll
            for (int d = 0; d < 4; ++d) {
                const int i0 = Hh * 8 + 2 * d;
                float h1a = v1[i0]     + (a1[i0]     - v1[i0])     * 0.5f;
                float h1b = v1[i0 + 1] + (a1[i0 + 1] - v1[i0 + 1]) * 0.5f;
                bool sa = h1a >= 1.f, sb = h1b >= 1.f;
                v1[i0]     = sa ? 0.f : h1a;
                v1[i0 + 1] = sb ? 0.f : h1b;
                unsigned int dw = (sa ? 0x3F80u : 0u) | (sb ? 0x3F800000u : 0u);
                if (Hh == 0) s0.u[d] = dw; else s1f.u[d] = dw;
            }
        const short8v S0 = s0.s, S1 = s1f.s;

        f32x4 acc[4];
#pragma unroll
        for (int T = 0; T < 4; ++T) {
            f32x4 c;
            c[0] = biasD[4 * T + 0]; c[1] = biasD[4 * T + 1];
            c[2] = biasD[4 * T + 2]; c[3] = biasD[4 * T + 3];
            c = __builtin_amdgcn_mfma_f32_16x16x32_bf16(Wlo[T][1], S1, c, 0, 0, 0);
            c = __builtin_amdgcn_mfma_f32_16x16x32_bf16(Wlo[T][0], S0, c, 0, 0, 0);
            c = __builtin_amdgcn_mfma_f32_16x16x32_bf16(Whi[T][1], S1, c, 0, 0, 0);
            c = __builtin_amdgcn_mfma_f32_16x16x32_bf16(Whi[T][0], S0, c, 0, 0, 0);
            acc[T] = c;
        }

        // LIF2 + spike count (D layout)
#pragma unroll
        for (int T = 0; T < 4; ++T)
#pragma unroll
            for (int q = 0; q < 4; ++q) {
                const int idx = 4 * T + q;
                float z  = acc[T][q];
                float h2 = v2[idx] + (z - v2[idx]) * 0.5f;
                bool s = h2 >= 1.f;
                v2[idx] = s ? 0.f : h2;
                cnt[idx] += s ? 1.f : 0.f;
            }
    }

    // --- classifier epilogue: logits = (cnt/64) @ cls_w.T + cls_b ---
    float p0 = 0.f, p1 = 0.f, p2 = 0.f, p3 = 0.f;
#pragma unroll
    for (int T = 0; T < 4; ++T)
#pragma unroll
        for (int q = 0; q < 4; ++q) {
            const int hp = 16 * T + 4 * grp + q;
            const float cv = cnt[4 * T + q];
            p0 = fmaf(cv, cls_w[0 * 64 + hp], p0);
            p1 = fmaf(cv, cls_w[1 * 64 + hp], p1);
            p2 = fmaf(cv, cls_w[2 * 64 + hp], p2);
            p3 = fmaf(cv, cls_w[3 * 64 + hp], p3);
        }
    p0 += __shfl_xor(p0, 16); p0 += __shfl_xor(p0, 32);
    p1 += __shfl_xor(p1, 16); p1 += __shfl_xor(p1, 32);
    p2 += __shfl_xor(p2, 16); p2 += __shfl_xor(p2, 32);
    p3 += __shfl_xor(p3, 16); p3 += __shfl_xor(p3, 32);
    if (lane < 16) {
        float4 o;
        o.x = p0 * (1.f / 64.f) + cls_b[0];
        o.y = p1 * (1.f / 64.f) + cls_b[1];
        o.z = p2 * (1.f / 64.f) + cls_b[2];
        o.w = p3 * (1.f / 64.f) + cls_b[3];
        *(float4*)&out[(size_t)(n0 + lane) * 4] = o;
    }
}

extern "C" void kernel_launch(void* const* d_in, const int* in_sizes, int n_in,
                              void* d_out, int out_size, void* d_ws, size_t ws_size,
                              hipStream_t stream) {
    const float* x     = (const float*)d_in[0];
    const float* fc1_w = (const float*)d_in[1];
    const float* fc1_b = (const float*)d_in[2];
    const float* bn1_g = (const float*)d_in[3];
    const float* bn1_b = (const float*)d_in[4];
    const float* bn1_m = (const float*)d_in[5];
    const float* bn1_v = (const float*)d_in[6];
    const float* fc2_w = (const float*)d_in[7];
    const float* fc2_b = (const float*)d_in[8];
    const float* bn2_g = (const float*)d_in[9];
    const float* bn2_b = (const float*)d_in[10];
    const float* bn2_m = (const float*)d_in[11];
    const float* bn2_v = (const float*)d_in[12];
    const float* cls_w = (const float*)d_in[13];
    const float* cls_b = (const float*)d_in[14];

    float* y = (float*)d_ws;  // [16384][64] f32 = 4 MB

    fc1_kernel<<<512, 256, 0, stream>>>(x, fc1_w, y);
    snn_kernel<<<256, 256, 0, stream>>>(y, fc1_b, bn1_g, bn1_b, bn1_m, bn1_v,
                                        fc2_w, fc2_b, bn2_g, bn2_b, bn2_m, bn2_v,
                                        cls_w, cls_b, (float*)d_out);
}

// Round 2
// 116.571 us; speedup vs baseline: 1.6556x; 1.6556x over previous
//
#include <hip/hip_runtime.h>
#include <hip/hip_bf16.h>

#define D_IN 1386
#define EPS 1e-5f
#define CHUNKS 44            // ceil(1386/32)

typedef __attribute__((ext_vector_type(8))) short short8v;
typedef __attribute__((ext_vector_type(4))) float f32x4;
typedef unsigned short ushortt;

__device__ inline unsigned short bf16rne(float f) {
    unsigned int u = __float_as_uint(f);
    u += 0x7FFFu + ((u >> 16) & 1u);
    return (unsigned short)(u >> 16);
}
__device__ inline float bfbits_to_f(unsigned short b) {
    return __uint_as_float(((unsigned int)b) << 16);
}

union S8U { short8v s; unsigned int u[4]; };

// ---------------- Kernel 0: precompute triple-split W1 in LDS-image order ---
// w3 image per chunk c (12288 B): 12 frag-groups g=3*T+s, each 64 lanes x 16 B.
// short index: c*6144 + g*512 + l*8 + j  ->  split_s( w[16T+(l&15)][32c+8*(l>>4)+j] )
__global__ __launch_bounds__(256) void prep_w3(const float* __restrict__ w,
                                               ushortt* __restrict__ w3) {
    int idx = blockIdx.x * 256 + threadIdx.x;
    if (idx >= CHUNKS * 6144) return;
    int c   = idx / 6144;
    int rem = idx - c * 6144;
    int g   = rem >> 9;
    int l   = (rem >> 3) & 63;
    int j   = rem & 7;
    int T   = g / 3, s = g - 3 * T;
    int h   = 16 * T + (l & 15);
    int k   = 32 * c + 8 * (l >> 4) + j;
    float v = (k < D_IN) ? w[h * D_IN + k] : 0.f;
    unsigned short hh = bf16rne(v);
    float r1 = v - bfbits_to_f(hh);
    unsigned short mm = bf16rne(r1);
    float r2 = r1 - bfbits_to_f(mm);
    unsigned short ll = bf16rne(r2);
    w3[idx] = (s == 0) ? hh : (s == 1) ? mm : ll;
}

// ---------------- Kernel 1: y = x @ fc1_w.T via triple-split bf16 MFMA ------
// Block: 256 thr = 4 waves, 64 samples. Wave: 16 samples x 64 h.
// A frag (x): lane l -> x[n0+(l&15)][32c + 8*(l>>4)+j]   (split in-register)
// B frag (w): lane l -> w[16T+(l&15)][32c + 8*(l>>4)+j]  (from LDS, dbuf)
// D: col(l&15)=h_local, row(4*(l>>4)+q)=sample_local  (verified convention)
__device__ inline void loadA(const float* __restrict__ xrow, int c, int g4,
                             float a[8]) {
    if (c < CHUNKS - 1) {
        const float2* p = (const float2*)(xrow + 32 * c);
#pragma unroll
        for (int i = 0; i < 4; ++i) {
            float2 v = p[i];
            a[2 * i] = v.x; a[2 * i + 1] = v.y;
        }
    } else {
#pragma unroll
        for (int j = 0; j < 8; ++j) {
            int kk = 8 * g4 + j;   // + 1376 = global k
            a[j] = (kk < D_IN - 32 * (CHUNKS - 1)) ? xrow[32 * (CHUNKS - 1) + j] : 0.f;
        }
    }
}

__global__ __launch_bounds__(256) void fc1_mfma(const float* __restrict__ x,
                                                const ushortt* __restrict__ w3,
                                                float* __restrict__ y) {
    __shared__ ushortt lds[2][6144];   // 2 x 12 KB
    const int t    = threadIdx.x;
    const int lane = t & 63;
    const int wid  = t >> 6;
    const int n0   = blockIdx.x * 64 + wid * 16;
    const int r    = lane & 15;
    const int g4   = lane >> 4;
    const float* xrow = x + (size_t)(n0 + r) * D_IN + 8 * g4;

    f32x4 acc[4];
#pragma unroll
    for (int T = 0; T < 4; ++T) acc[T] = (f32x4){0.f, 0.f, 0.f, 0.f};

    // prologue: stage chunk 0, load A chunk 0
    float a[8];
    loadA(xrow, 0, g4, a);
    {
        const float4* s = (const float4*)w3 + t;
        float4* dst = (float4*)&lds[0][0];
        dst[t] = s[0]; dst[t + 256] = s[256]; dst[t + 512] = s[512];
    }
    __syncthreads();

#pragma unroll 2
    for (int c = 0; c < CHUNKS; ++c) {
        const int buf = c & 1;
        float anext[8];
        float4 snext[3];
        if (c < CHUNKS - 1) {
            loadA(xrow, c + 1, g4, anext);
            const float4* s = (const float4*)w3 + (size_t)(c + 1) * 768 + t;
            snext[0] = s[0]; snext[1] = s[256]; snext[2] = s[512];
        }
        // split A into hi/mid/lo bf16 fragments
        S8U Ah, Am, Al;
#pragma unroll
        for (int d = 0; d < 4; ++d) {
            float v0 = a[2 * d], v1 = a[2 * d + 1];
            unsigned short h0 = bf16rne(v0), h1 = bf16rne(v1);
            float r10 = v0 - bfbits_to_f(h0), r11 = v1 - bfbits_to_f(h1);
            unsigned short m0 = bf16rne(r10), m1 = bf16rne(r11);
            float r20 = r10 - bfbits_to_f(m0), r21 = r11 - bfbits_to_f(m1);
            unsigned short l0 = bf16rne(r20), l1 = bf16rne(r21);
            Ah.u[d] = (unsigned int)h0 | ((unsigned int)h1 << 16);
            Am.u[d] = (unsigned int)m0 | ((unsigned int)m1 << 16);
            Al.u[d] = (unsigned int)l0 | ((unsigned int)l1 << 16);
        }
        const short8v XH = Ah.s, XM = Am.s, XL = Al.s;
#pragma unroll
        for (int T = 0; T < 4; ++T) {
            short8v Bh = *(const short8v*)&lds[buf][(3 * T + 0) * 512 + lane * 8];
            short8v Bm = *(const short8v*)&lds[buf][(3 * T + 1) * 512 + lane * 8];
            short8v Bl = *(const short8v*)&lds[buf][(3 * T + 2) * 512 + lane * 8];
            f32x4 cacc = acc[T];
            cacc = __builtin_amdgcn_mfma_f32_16x16x32_bf16(XL, Bh, cacc, 0, 0, 0);
            cacc = __builtin_amdgcn_mfma_f32_16x16x32_bf16(XM, Bm, cacc, 0, 0, 0);
            cacc = __builtin_amdgcn_mfma_f32_16x16x32_bf16(XH, Bl, cacc, 0, 0, 0);
            cacc = __builtin_amdgcn_mfma_f32_16x16x32_bf16(XM, Bh, cacc, 0, 0, 0);
            cacc = __builtin_amdgcn_mfma_f32_16x16x32_bf16(XH, Bm, cacc, 0, 0, 0);
            cacc = __builtin_amdgcn_mfma_f32_16x16x32_bf16(XH, Bh, cacc, 0, 0, 0);
            acc[T] = cacc;
        }
        if (c < CHUNKS - 1) {
            float4* dst = (float4*)&lds[buf ^ 1][0];
            dst[t] = snext[0]; dst[t + 256] = snext[1]; dst[t + 512] = snext[2];
#pragma unroll
            for (int j = 0; j < 8; ++j) a[j] = anext[j];
        }
        __syncthreads();
    }

#pragma unroll
    for (int T = 0; T < 4; ++T)
#pragma unroll
        for (int q = 0; q < 4; ++q)
            y[(size_t)(n0 + 4 * g4 + q) * 64 + 16 * T + r] = acc[T][q];
}

// ---------------- Kernel 2: 64-step LIF recurrence via MFMA (unchanged) -----
__global__ __launch_bounds__(256) void snn_kernel(
    const float* __restrict__ y,
    const float* __restrict__ fc1_b,
    const float* __restrict__ bn1_g, const float* __restrict__ bn1_b,
    const float* __restrict__ bn1_m, const float* __restrict__ bn1_v,
    const float* __restrict__ fc2_w, const float* __restrict__ fc2_b,
    const float* __restrict__ bn2_g, const float* __restrict__ bn2_b,
    const float* __restrict__ bn2_m, const float* __restrict__ bn2_v,
    const float* __restrict__ cls_w, const float* __restrict__ cls_b,
    float* __restrict__ out)
{
    const int lane = threadIdx.x & 63;
    const int wid  = threadIdx.x >> 6;
    const int n0   = blockIdx.x * 64 + wid * 16;
    const int r    = lane & 15;
    const int grp  = lane >> 4;

    short8v Whi[4][2], Wlo[4][2];
#pragma unroll
    for (int T = 0; T < 4; ++T) {
        const int hp = 16 * T + r;
        const float scale = bn2_g[hp] / sqrtf(bn2_v[hp] + EPS);
#pragma unroll
        for (int Hh = 0; Hh < 2; ++Hh) {
            S8U hi, lo;
#pragma unroll
            for (int d = 0; d < 4; ++d) {
                const int kk = 32 * Hh + 8 * grp + 2 * d;
                float w0 = fc2_w[hp * 64 + kk]     * scale;
                float w1 = fc2_w[hp * 64 + kk + 1] * scale;
                unsigned short h0 = bf16rne(w0), h1 = bf16rne(w1);
                unsigned short l0 = bf16rne(w0 - bfbits_to_f(h0));
                unsigned short l1 = bf16rne(w1 - bfbits_to_f(h1));
                hi.u[d] = (unsigned int)h0 | ((unsigned int)h1 << 16);
                lo.u[d] = (unsigned int)l0 | ((unsigned int)l1 << 16);
            }
            Whi[T][Hh] = hi.s;
            Wlo[T][Hh] = lo.s;
        }
    }

    float a1[16];
#pragma unroll
    for (int Hh = 0; Hh < 2; ++Hh)
#pragma unroll
        for (int e = 0; e < 8; ++e) {
            const int hin = 32 * Hh + 8 * grp + e;
            float yv = y[(size_t)(n0 + r) * 64 + hin] + fc1_b[hin];
            float s1v = bn1_g[hin] / sqrtf(bn1_v[hin] + EPS);
            a1[Hh * 8 + e] = (yv - bn1_m[hin]) * s1v + bn1_b[hin];
        }

    float biasD[16];
#pragma unroll
    for (int T = 0; T < 4; ++T)
#pragma unroll
        for (int q = 0; q < 4; ++q) {
            const int hp = 16 * T + 4 * grp + q;
            const float scale = bn2_g[hp] / sqrtf(bn2_v[hp] + EPS);
            biasD[4 * T + q] = (fc2_b[hp] - bn2_m[hp]) * scale + bn2_b[hp];
        }

    float v1[16], v2[16], cnt[16];
#pragma unroll
    for (int i = 0; i < 16; ++i) { v1[i] = 0.f; v2[i] = 0.f; cnt[i] = 0.f; }

#pragma unroll 2
    for (int t = 0; t < 64; ++t) {
        S8U s0, s1f;
#pragma unroll
        for (int Hh = 0; Hh < 2; ++Hh)
#pragma unroll
            for (int d = 0; d < 4; ++d) {
                const int i0 = Hh * 8 + 2 * d;
                float h1a = v1[i0]     + (a1[i0]     - v1[i0])     * 0.5f;
                float h1b = v1[i0 + 1] + (a1[i0 + 1] - v1[i0 + 1]) * 0.5f;
                bool sa = h1a >= 1.f, sb = h1b >= 1.f;
                v1[i0]     = sa ? 0.f : h1a;
                v1[i0 + 1] = sb ? 0.f : h1b;
                unsigned int dw = (sa ? 0x3F80u : 0u) | (sb ? 0x3F800000u : 0u);
                if (Hh == 0) s0.u[d] = dw; else s1f.u[d] = dw;
            }
        const short8v S0 = s0.s, S1 = s1f.s;

        f32x4 acc[4];
#pragma unroll
        for (int T = 0; T < 4; ++T) {
            f32x4 c;
            c[0] = biasD[4 * T + 0]; c[1] = biasD[4 * T + 1];
            c[2] = biasD[4 * T + 2]; c[3] = biasD[4 * T + 3];
            c = __builtin_amdgcn_mfma_f32_16x16x32_bf16(Wlo[T][1], S1, c, 0, 0, 0);
            c = __builtin_amdgcn_mfma_f32_16x16x32_bf16(Wlo[T][0], S0, c, 0, 0, 0);
            c = __builtin_amdgcn_mfma_f32_16x16x32_bf16(Whi[T][1], S1, c, 0, 0, 0);
            c = __builtin_amdgcn_mfma_f32_16x16x32_bf16(Whi[T][0], S0, c, 0, 0, 0);
            acc[T] = c;
        }

#pragma unroll
        for (int T = 0; T < 4; ++T)
#pragma unroll
            for (int q = 0; q < 4; ++q) {
                const int idx = 4 * T + q;
                float z  = acc[T][q];
                float h2 = v2[idx] + (z - v2[idx]) * 0.5f;
                bool s = h2 >= 1.f;
                v2[idx] = s ? 0.f : h2;
                cnt[idx] += s ? 1.f : 0.f;
            }
    }

    float p0 = 0.f, p1 = 0.f, p2 = 0.f, p3 = 0.f;
#pragma unroll
    for (int T = 0; T < 4; ++T)
#pragma unroll
        for (int q = 0; q < 4; ++q) {
            const int hp = 16 * T + 4 * grp + q;
            const float cv = cnt[4 * T + q];
            p0 = fmaf(cv, cls_w[0 * 64 + hp], p0);
            p1 = fmaf(cv, cls_w[1 * 64 + hp], p1);
            p2 = fmaf(cv, cls_w[2 * 64 + hp], p2);
            p3 = fmaf(cv, cls_w[3 * 64 + hp], p3);
        }
    p0 += __shfl_xor(p0, 16); p0 += __shfl_xor(p0, 32);
    p1 += __shfl_xor(p1, 16); p1 += __shfl_xor(p1, 32);
    p2 += __shfl_xor(p2, 16); p2 += __shfl_xor(p2, 32);
    p3 += __shfl_xor(p3, 16); p3 += __shfl_xor(p3, 32);
    if (lane < 16) {
        float4 o;
        o.x = p0 * (1.f / 64.f) + cls_b[0];
        o.y = p1 * (1.f / 64.f) + cls_b[1];
        o.z = p2 * (1.f / 64.f) + cls_b[2];
        o.w = p3 * (1.f / 64.f) + cls_b[3];
        *(float4*)&out[(size_t)(n0 + lane) * 4] = o;
    }
}

extern "C" void kernel_launch(void* const* d_in, const int* in_sizes, int n_in,
                              void* d_out, int out_size, void* d_ws, size_t ws_size,
                              hipStream_t stream) {
    const float* x     = (const float*)d_in[0];
    const float* fc1_w = (const float*)d_in[1];
    const float* fc1_b = (const float*)d_in[2];
    const float* bn1_g = (const float*)d_in[3];
    const float* bn1_b = (const float*)d_in[4];
    const float* bn1_m = (const float*)d_in[5];
    const float* bn1_v = (const float*)d_in[6];
    const float* fc2_w = (const float*)d_in[7];
    const float* fc2_b = (const float*)d_in[8];
    const float* bn2_g = (const float*)d_in[9];
    const float* bn2_b = (const float*)d_in[10];
    const float* bn2_m = (const float*)d_in[11];
    const float* bn2_v = (const float*)d_in[12];
    const float* cls_w = (const float*)d_in[13];
    const float* cls_b = (const float*)d_in[14];

    float*   y  = (float*)d_ws;                            // 4 MB
    ushortt* w3 = (ushortt*)((char*)d_ws + (4 << 20));     // 528 KB

    prep_w3 <<<1056, 256, 0, stream>>>(fc1_w, w3);
    fc1_mfma<<<256,  256, 0, stream>>>(x, w3, y);
    snn_kernel<<<256, 256, 0, stream>>>(y, fc1_b, bn1_g, bn1_b, bn1_m, bn1_v,
                                        fc2_w, fc2_b, bn2_g, bn2_b, bn2_m, bn2_v,
                                        cls_w, cls_b, (float*)d_out);
}

// Round 3
// 74.753 us; speedup vs baseline: 2.5818x; 1.5594x over previous
//
#include <hip/hip_runtime.h>
#include <hip/hip_bf16.h>

#define D_IN 1386
#define EPS 1e-5f
#define CHUNKS 44            // ceil(1386/32)

typedef __attribute__((ext_vector_type(8))) short short8v;
typedef __attribute__((ext_vector_type(4))) float f32x4;
typedef unsigned short ushortt;

__device__ inline unsigned short bf16rne(float f) {
    unsigned int u = __float_as_uint(f);
    u += 0x7FFFu + ((u >> 16) & 1u);
    return (unsigned short)(u >> 16);
}
__device__ inline float bfbits_to_f(unsigned short b) {
    return __uint_as_float(((unsigned int)b) << 16);
}

union S8U { short8v s; unsigned int u[4]; };

// packed pair f32->bf16 (RNE, v_cvt_pk_bf16_f32) + residuals
__device__ inline unsigned int cvt2(float v0, float v1, float& r0, float& r1) {
    union { __hip_bfloat162 b2; unsigned int u; } cv;
    cv.b2 = __float22bfloat162_rn(make_float2(v0, v1));
    r0 = v0 - __uint_as_float((cv.u & 0xFFFFu) << 16);
    r1 = v1 - __uint_as_float(cv.u & 0xFFFF0000u);
    return cv.u;
}
__device__ inline unsigned int cvt2n(float v0, float v1) {
    union { __hip_bfloat162 b2; unsigned int u; } cv;
    cv.b2 = __float22bfloat162_rn(make_float2(v0, v1));
    return cv.u;
}

// ---------------- Kernel 0: precompute triple-split W1 in frag-image order --
// short index: c*6144 + g*512 + l*8 + j -> split_s( w[16T+(l&15)][32c+8*(l>>4)+j] )
// with g = 3*T + s
__global__ __launch_bounds__(256) void prep_w3(const float* __restrict__ w,
                                               ushortt* __restrict__ w3) {
    int idx = blockIdx.x * 256 + threadIdx.x;
    if (idx >= CHUNKS * 6144) return;
    int c   = idx / 6144;
    int rem = idx - c * 6144;
    int g   = rem >> 9;
    int l   = (rem >> 3) & 63;
    int j   = rem & 7;
    int T   = g / 3, s = g - 3 * T;
    int h   = 16 * T + (l & 15);
    int k   = 32 * c + 8 * (l >> 4) + j;
    float v = (k < D_IN) ? w[h * D_IN + k] : 0.f;
    unsigned short hh = bf16rne(v);
    float r1 = v - bfbits_to_f(hh);
    unsigned short mm = bf16rne(r1);
    float r2 = r1 - bfbits_to_f(mm);
    unsigned short ll = bf16rne(r2);
    w3[idx] = (s == 0) ? hh : (s == 1) ? mm : ll;
}

// ---------------- Kernel 1: y = x @ fc1_w.T, K-split x4, barrier-free loop --
// Block: 256 thr = 4 waves, ONE 16-sample group; wave `wid` owns chunks
// [11*wid, 11*wid+11). B frags straight from w3 (L2). Final LDS reduction.
__device__ inline void loadA(const float* __restrict__ xrow, int c, int g4,
                             float a[8]) {
    if (c < CHUNKS - 1) {
        const float2* p = (const float2*)(xrow + 32 * c);
#pragma unroll
        for (int i = 0; i < 4; ++i) {
            float2 v = p[i];
            a[2 * i] = v.x; a[2 * i + 1] = v.y;
        }
    } else {
#pragma unroll
        for (int j = 0; j < 8; ++j) {
            int kk = 8 * g4 + j;   // + 1376 = global k
            a[j] = (kk < D_IN - 32 * (CHUNKS - 1)) ? xrow[32 * (CHUNKS - 1) + j] : 0.f;
        }
    }
}

__global__ __launch_bounds__(256, 4) void fc1_mfma(const float* __restrict__ x,
                                                   const ushortt* __restrict__ w3,
                                                   float* __restrict__ y) {
    __shared__ float red[4][64][16];   // 16 KB, used once at the end
    const int t    = threadIdx.x;
    const int lane = t & 63;
    const int wid  = t >> 6;
    const int n0   = blockIdx.x * 16;
    const int r    = lane & 15;
    const int g4   = lane >> 4;
    const float* xrow = x + (size_t)(n0 + r) * D_IN + 8 * g4;

    f32x4 acc[4];
#pragma unroll
    for (int T = 0; T < 4; ++T) acc[T] = (f32x4){0.f, 0.f, 0.f, 0.f};

    float a[8];
    loadA(xrow, 11 * wid, g4, a);

#pragma unroll 1
    for (int i = 0; i < 11; ++i) {
        const int c = 11 * wid + i;
        // prefetch next A (long latency path: HBM/L3)
        float an[8];
        if (i < 10) loadA(xrow, c + 1, g4, an);
        // B fragments for this chunk (12 x 16B coalesced, L2-hot)
        const short8v* bp = (const short8v*)(w3 + (size_t)c * 6144) + lane;
        short8v B0  = bp[0 * 64],  B1  = bp[1 * 64],  B2  = bp[2 * 64];
        short8v B3  = bp[3 * 64],  B4  = bp[4 * 64],  B5  = bp[5 * 64];
        short8v B6  = bp[6 * 64],  B7  = bp[7 * 64],  B8  = bp[8 * 64];
        short8v B9  = bp[9 * 64],  B10 = bp[10 * 64], B11 = bp[11 * 64];
        // triple-split A in-register (cvt_pk based)
        S8U Ah, Am, Al;
#pragma unroll
        for (int d = 0; d < 4; ++d) {
            float m0, m1, l0, l1;
            Ah.u[d] = cvt2(a[2 * d], a[2 * d + 1], m0, m1);
            Am.u[d] = cvt2(m0, m1, l0, l1);
            Al.u[d] = cvt2n(l0, l1);
        }
        const short8v XH = Ah.s, XM = Am.s, XL = Al.s;
#pragma unroll
        for (int T = 0; T < 4; ++T) {
            const short8v Bh = (T == 0) ? B0 : (T == 1) ? B3 : (T == 2) ? B6 : B9;
            const short8v Bm = (T == 0) ? B1 : (T == 1) ? B4 : (T == 2) ? B7 : B10;
            const short8v Bl = (T == 0) ? B2 : (T == 1) ? B5 : (T == 2) ? B8 : B11;
            f32x4 cacc = acc[T];
            cacc = __builtin_amdgcn_mfma_f32_16x16x32_bf16(XL, Bh, cacc, 0, 0, 0);
            cacc = __builtin_amdgcn_mfma_f32_16x16x32_bf16(XM, Bm, cacc, 0, 0, 0);
            cacc = __builtin_amdgcn_mfma_f32_16x16x32_bf16(XH, Bl, cacc, 0, 0, 0);
            cacc = __builtin_amdgcn_mfma_f32_16x16x32_bf16(XM, Bh, cacc, 0, 0, 0);
            cacc = __builtin_amdgcn_mfma_f32_16x16x32_bf16(XH, Bm, cacc, 0, 0, 0);
            cacc = __builtin_amdgcn_mfma_f32_16x16x32_bf16(XH, Bh, cacc, 0, 0, 0);
            acc[T] = cacc;
        }
#pragma unroll
        for (int j = 0; j < 8; ++j) a[j] = an[j];
    }

    // cross-wave K reduction via LDS (single barrier)
#pragma unroll
    for (int T = 0; T < 4; ++T)
#pragma unroll
        for (int q = 0; q < 4; ++q)
            red[wid][lane][4 * T + q] = acc[T][q];
    __syncthreads();
#pragma unroll
    for (int q = 0; q < 4; ++q) {
        float s = red[0][lane][4 * wid + q] + red[1][lane][4 * wid + q]
                + red[2][lane][4 * wid + q] + red[3][lane][4 * wid + q];
        y[(size_t)(n0 + 4 * g4 + q) * 64 + 16 * wid + r] = s;
    }
}

// ---------------- Kernel 2: 64-step LIF recurrence via MFMA (unchanged) -----
__global__ __launch_bounds__(256) void snn_kernel(
    const float* __restrict__ y,
    const float* __restrict__ fc1_b,
    const float* __restrict__ bn1_g, const float* __restrict__ bn1_b,
    const float* __restrict__ bn1_m, const float* __restrict__ bn1_v,
    const float* __restrict__ fc2_w, const float* __restrict__ fc2_b,
    const float* __restrict__ bn2_g, const float* __restrict__ bn2_b,
    const float* __restrict__ bn2_m, const float* __restrict__ bn2_v,
    const float* __restrict__ cls_w, const float* __restrict__ cls_b,
    float* __restrict__ out)
{
    const int lane = threadIdx.x & 63;
    const int wid  = threadIdx.x >> 6;
    const int n0   = blockIdx.x * 64 + wid * 16;
    const int r    = lane & 15;
    const int grp  = lane >> 4;

    short8v Whi[4][2], Wlo[4][2];
#pragma unroll
    for (int T = 0; T < 4; ++T) {
        const int hp = 16 * T + r;
        const float scale = bn2_g[hp] / sqrtf(bn2_v[hp] + EPS);
#pragma unroll
        for (int Hh = 0; Hh < 2; ++Hh) {
            S8U hi, lo;
#pragma unroll
            for (int d = 0; d < 4; ++d) {
                const int kk = 32 * Hh + 8 * grp + 2 * d;
                float w0 = fc2_w[hp * 64 + kk]     * scale;
                float w1 = fc2_w[hp * 64 + kk + 1] * scale;
                unsigned short h0 = bf16rne(w0), h1 = bf16rne(w1);
                unsigned short l0 = bf16rne(w0 - bfbits_to_f(h0));
                unsigned short l1 = bf16rne(w1 - bfbits_to_f(h1));
                hi.u[d] = (unsigned int)h0 | ((unsigned int)h1 << 16);
                lo.u[d] = (unsigned int)l0 | ((unsigned int)l1 << 16);
            }
            Whi[T][Hh] = hi.s;
            Wlo[T][Hh] = lo.s;
        }
    }

    float a1[16];
#pragma unroll
    for (int Hh = 0; Hh < 2; ++Hh)
#pragma unroll
        for (int e = 0; e < 8; ++e) {
            const int hin = 32 * Hh + 8 * grp + e;
            float yv = y[(size_t)(n0 + r) * 64 + hin] + fc1_b[hin];
            float s1v = bn1_g[hin] / sqrtf(bn1_v[hin] + EPS);
            a1[Hh * 8 + e] = (yv - bn1_m[hin]) * s1v + bn1_b[hin];
        }

    float biasD[16];
#pragma unroll
    for (int T = 0; T < 4; ++T)
#pragma unroll
        for (int q = 0; q < 4; ++q) {
            const int hp = 16 * T + 4 * grp + q;
            const float scale = bn2_g[hp] / sqrtf(bn2_v[hp] + EPS);
            biasD[4 * T + q] = (fc2_b[hp] - bn2_m[hp]) * scale + bn2_b[hp];
        }

    float v1[16], v2[16], cnt[16];
#pragma unroll
    for (int i = 0; i < 16; ++i) { v1[i] = 0.f; v2[i] = 0.f; cnt[i] = 0.f; }

#pragma unroll 2
    for (int t = 0; t < 64; ++t) {
        S8U s0, s1f;
#pragma unroll
        for (int Hh = 0; Hh < 2; ++Hh)
#pragma unroll
            for (int d = 0; d < 4; ++d) {
                const int i0 = Hh * 8 + 2 * d;
                float h1a = v1[i0]     + (a1[i0]     - v1[i0])     * 0.5f;
                float h1b = v1[i0 + 1] + (a1[i0 + 1] - v1[i0 + 1]) * 0.5f;
                bool sa = h1a >= 1.f, sb = h1b >= 1.f;
                v1[i0]     = sa ? 0.f : h1a;
                v1[i0 + 1] = sb ? 0.f : h1b;
                unsigned int dw = (sa ? 0x3F80u : 0u) | (sb ? 0x3F800000u : 0u);
                if (Hh == 0) s0.u[d] = dw; else s1f.u[d] = dw;
            }
        const short8v S0 = s0.s, S1 = s1f.s;

        f32x4 acc[4];
#pragma unroll
        for (int T = 0; T < 4; ++T) {
            f32x4 c;
            c[0] = biasD[4 * T + 0]; c[1] = biasD[4 * T + 1];
            c[2] = biasD[4 * T + 2]; c[3] = biasD[4 * T + 3];
            c = __builtin_amdgcn_mfma_f32_16x16x32_bf16(Wlo[T][1], S1, c, 0, 0, 0);
            c = __builtin_amdgcn_mfma_f32_16x16x32_bf16(Wlo[T][0], S0, c, 0, 0, 0);
            c = __builtin_amdgcn_mfma_f32_16x16x32_bf16(Whi[T][1], S1, c, 0, 0, 0);
            c = __builtin_amdgcn_mfma_f32_16x16x32_bf16(Whi[T][0], S0, c, 0, 0, 0);
            acc[T] = c;
        }

#pragma unroll
        for (int T = 0; T < 4; ++T)
#pragma unroll
            for (int q = 0; q < 4; ++q) {
                const int idx = 4 * T + q;
                float z  = acc[T][q];
                float h2 = v2[idx] + (z - v2[idx]) * 0.5f;
                bool s = h2 >= 1.f;
                v2[idx] = s ? 0.f : h2;
                cnt[idx] += s ? 1.f : 0.f;
            }
    }

    float p0 = 0.f, p1 = 0.f, p2 = 0.f, p3 = 0.f;
#pragma unroll
    for (int T = 0; T < 4; ++T)
#pragma unroll
        for (int q = 0; q < 4; ++q) {
            const int hp = 16 * T + 4 * grp + q;
            const float cv = cnt[4 * T + q];
            p0 = fmaf(cv, cls_w[0 * 64 + hp], p0);
            p1 = fmaf(cv, cls_w[1 * 64 + hp], p1);
            p2 = fmaf(cv, cls_w[2 * 64 + hp], p2);
            p3 = fmaf(cv, cls_w[3 * 64 + hp], p3);
        }
    p0 += __shfl_xor(p0, 16); p0 += __shfl_xor(p0, 32);
    p1 += __shfl_xor(p1, 16); p1 += __shfl_xor(p1, 32);
    p2 += __shfl_xor(p2, 16); p2 += __shfl_xor(p2, 32);
    p3 += __shfl_xor(p3, 16); p3 += __shfl_xor(p3, 32);
    if (lane < 16) {
        float4 o;
        o.x = p0 * (1.f / 64.f) + cls_b[0];
        o.y = p1 * (1.f / 64.f) + cls_b[1];
        o.z = p2 * (1.f / 64.f) + cls_b[2];
        o.w = p3 * (1.f / 64.f) + cls_b[3];
        *(float4*)&out[(size_t)(n0 + lane) * 4] = o;
    }
}

extern "C" void kernel_launch(void* const* d_in, const int* in_sizes, int n_in,
                              void* d_out, int out_size, void* d_ws, size_t ws_size,
                              hipStream_t stream) {
    const float* x     = (const float*)d_in[0];
    const float* fc1_w = (const float*)d_in[1];
    const float* fc1_b = (const float*)d_in[2];
    const float* bn1_g = (const float*)d_in[3];
    const float* bn1_b = (const float*)d_in[4];
    const float* bn1_m = (const float*)d_in[5];
    const float* bn1_v = (const float*)d_in[6];
    const float* fc2_w = (const float*)d_in[7];
    const float* fc2_b = (const float*)d_in[8];
    const float* bn2_g = (const float*)d_in[9];
    const float* bn2_b = (const float*)d_in[10];
    const float* bn2_m = (const float*)d_in[11];
    const float* bn2_v = (const float*)d_in[12];
    const float* cls_w = (const float*)d_in[13];
    const float* cls_b = (const float*)d_in[14];

    float*   y  = (float*)d_ws;                            // 4 MB
    ushortt* w3 = (ushortt*)((char*)d_ws + (4 << 20));     // 528 KB

    prep_w3 <<<1056, 256, 0, stream>>>(fc1_w, w3);
    fc1_mfma<<<1024, 256, 0, stream>>>(x, w3, y);
    snn_kernel<<<256, 256, 0, stream>>>(y, fc1_b, bn1_g, bn1_b, bn1_m, bn1_v,
                                        fc2_w, fc2_b, bn2_g, bn2_b, bn2_m, bn2_v,
                                        cls_w, cls_b, (float*)d_out);
}